// Round 1
// baseline (272.583 us; speedup 1.0000x reference)
//
#include <hip/hip_runtime.h>
#include <hip/hip_bf16.h>
#include <math.h>

#define D_MODEL 128
#define D_STATE 64
#define LEN 1024
#define BATCH 32

// ---------------- Chebyshev poly6 GELU ----------------
__device__ __forceinline__ float gelu_cheb(float x) {
    float t = (2.0f * x - 10.0f) * 0.05f;   // (2x - (hi+lo)) / (hi-lo), lo=-5 hi=15
    float r = 6.04831644882f + 8.094460228971f * t;
    float tm1 = 1.0f, tc = t;
    float t2 = 2.0f * t * tc - tm1; r += 1.371512430522f  * t2;
    float t3 = 2.0f * t * t2 - tc;  r += -0.740775295685f * t3;
    float t4 = 2.0f * t * t3 - t2;  r += 0.134773988002f  * t4;
    float t5 = 2.0f * t * t4 - t3;  r += 0.126019270103f  * t5;
    float t6 = 2.0f * t * t5 - t4;  r += -0.239569101196f * t6;
    return r;
}

// ---------------- Kernel 1: per-(d,n) S4D parameters ----------------
// dtA = A*dt ; a = Cc * B_bar, B_bar = (A_bar-1)/A * Bc
__global__ void k_params(const float* __restrict__ log_dt, const float* __restrict__ log_A_real,
                         const float* __restrict__ A_imag, const float* __restrict__ B_re,
                         const float* __restrict__ B_im, const float* __restrict__ C_re,
                         const float* __restrict__ C_im,
                         float* __restrict__ dtA_re, float* __restrict__ dtA_im,
                         float* __restrict__ a_re, float* __restrict__ a_im) {
    int d = blockIdx.x;
    int n = threadIdx.x;
    int idx = d * D_STATE + n;
    float dt  = expf(log_dt[d]);
    float Are = -expf(log_A_real[idx]);
    float Aim = A_imag[idx];
    float dre = Are * dt, dim = Aim * dt;
    // A_bar = exp(dre + i*dim)
    float e = expf(dre);
    float sn, cs; sincosf(dim, &sn, &cs);
    float Abr = e * cs, Abi = e * sn;
    // (A_bar - 1) / A
    float numr = Abr - 1.0f, numi = Abi;
    float den = Are * Are + Aim * Aim;
    float inv = 1.0f / den;
    float qr = (numr * Are + numi * Aim) * inv;
    float qi = (numi * Are - numr * Aim) * inv;
    // * Bc
    float Br = B_re[idx], Bi = B_im[idx];
    float Bbr = qr * Br - qi * Bi;
    float Bbi = qr * Bi + qi * Br;
    // a = Cc * B_bar
    float Cr = C_re[idx], Ci = C_im[idx];
    float ar = Cr * Bbr - Ci * Bbi;
    float ai = Cr * Bbi + Ci * Bbr;
    dtA_re[idx] = dre; dtA_im[idx] = dim;
    a_re[idx] = ar;    a_im[idx] = ai;
}

// ---------------- Kernel 2: K[d][l] = Re( sum_n a_n * exp(dtA_n * l) ) ----------------
__global__ __launch_bounds__(256) void k_genK(const float* __restrict__ dtA_re,
                                              const float* __restrict__ dtA_im,
                                              const float* __restrict__ a_re,
                                              const float* __restrict__ a_im,
                                              float* __restrict__ K) {
    int d = blockIdx.x;
    int l = blockIdx.y * blockDim.x + threadIdx.x;
    float fl = (float)l;
    float acc = 0.0f;
    int base = d * D_STATE;
    for (int n = 0; n < D_STATE; ++n) {
        float e = expf(dtA_re[base + n] * fl);
        float sn, cs; sincosf(dtA_im[base + n] * fl, &sn, &cs);
        acc += e * (a_re[base + n] * cs - a_im[base + n] * sn);
    }
    K[d * LEN + l] = acc;
}

// ---------------- Kernel 3: depthwise conv + skip + GELU poly ----------------
// out[l] = sum_{j=0..l} u[j] * K[j + L-1 - l]; thread t -> outputs l0=4t..4t+3
__global__ __launch_bounds__(256) void k_conv(const float* __restrict__ u,
                                              const float* __restrict__ K,
                                              const float* __restrict__ Dp,
                                              float* __restrict__ pg) {
    __shared__ float u_s[LEN];
    __shared__ float k_s[LEN];
    int b = blockIdx.x >> 7;
    int d = blockIdx.x & 127;
    const float* up = u + (size_t)(b * D_MODEL + d) * LEN;
    const float* kp = K + (size_t)d * LEN;
    int t = threadIdx.x;
    ((float4*)u_s)[t] = ((const float4*)up)[t];
    ((float4*)k_s)[t] = ((const float4*)kp)[t];
    __syncthreads();

    float Dd = Dp[d];
    int l0 = 4 * t;
    int s0 = (LEN - 1) - l0;           // 1023 - 4t
    float acc0 = 0.f, acc1 = 0.f, acc2 = 0.f, acc3 = 0.f;
    // kA covers k_s[s0-3 .. s0] (16B aligned since s0-3 = 1020-4t)
    float4 kA = *(const float4*)&k_s[s0 - 3];
    for (int J = 0; J < t; ++J) {
        float4 u4 = *(const float4*)&u_s[4 * J];
        float4 kB = *(const float4*)&k_s[4 * J + s0 + 1];
        // j = 4J+m ; out[l0+i] needs K[j + s0 - i]
        acc0 += u4.x * kA.w; acc1 += u4.x * kA.z; acc2 += u4.x * kA.y; acc3 += u4.x * kA.x;
        acc0 += u4.y * kB.x; acc1 += u4.y * kA.w; acc2 += u4.y * kA.z; acc3 += u4.y * kA.y;
        acc0 += u4.z * kB.y; acc1 += u4.z * kB.x; acc2 += u4.z * kA.w; acc3 += u4.z * kA.z;
        acc0 += u4.w * kB.z; acc1 += u4.w * kB.y; acc2 += u4.w * kB.x; acc3 += u4.w * kA.w;
        kA = kB;
    }
    // tail: j = 4t+jj, jj <= i ; K index = 1023 + jj - i ; kA now = k_s[1020..1023]
    float4 u4 = *(const float4*)&u_s[l0];
    acc0 += u4.x * kA.w;
    acc1 += u4.x * kA.z + u4.y * kA.w;
    acc2 += u4.x * kA.y + u4.y * kA.z + u4.z * kA.w;
    acc3 += u4.x * kA.x + u4.y * kA.y + u4.z * kA.z + u4.w * kA.w;

    float4 outv;
    outv.x = gelu_cheb(acc0 + u4.x * Dd);
    outv.y = gelu_cheb(acc1 + u4.y * Dd);
    outv.z = gelu_cheb(acc2 + u4.z * Dd);
    outv.w = gelu_cheb(acc3 + u4.w * Dd);
    ((float4*)(pg + (size_t)(b * D_MODEL + d) * LEN))[t] = outv;
}

// ---------------- Kernel 4: W1 matmul + linear-gate GLU + Wdec-folded pooling ----------------
// grid: 32*16 blocks, 256 threads = 64 l-positions x 4 o-quarters
__global__ __launch_bounds__(256) void k_glu(const float* __restrict__ pg,
                                             const float* __restrict__ W1,
                                             const float* __restrict__ b1,
                                             const float* __restrict__ Wdec,
                                             float* __restrict__ acc) {
    int blk = blockIdx.x;
    int b = blk >> 4;
    int lb = blk & 15;
    int lane = threadIdx.x & 63;
    int h = __builtin_amdgcn_readfirstlane(threadIdx.x >> 6);  // wave-uniform -> scalar W1 loads
    int l = lb * 64 + lane;

    const float* xb = pg + (size_t)b * D_MODEL * LEN + l;
    float x[D_MODEL];
#pragma unroll
    for (int k = 0; k < D_MODEL; ++k) x[k] = xb[k * LEN];

    float s = 0.0f;
    int o0 = h * 32;
    for (int oi = 0; oi < 32; ++oi) {
        int o = o0 + oi;
        const float* w1a = W1 + o * D_MODEL;
        const float* w1b = W1 + (o + D_MODEL) * D_MODEL;
        float aa = b1[o];
        float bb = b1[o + D_MODEL];
#pragma unroll
        for (int k = 0; k < D_MODEL; ++k) {
            aa += w1a[k] * x[k];
            bb += w1b[k] * x[k];
        }
        float g = 0.25f * bb + 0.5f;
        g = fminf(fmaxf(g, 0.0f), 1.0f);
        s += Wdec[o] * aa * g;
    }
#pragma unroll
    for (int off = 32; off > 0; off >>= 1) s += __shfl_down(s, off, 64);
    if (lane == 0) atomicAdd(&acc[b], s);
}

// ---------------- Kernel 5: finalize ----------------
__global__ void k_finish(const float* __restrict__ acc, const float* __restrict__ bdec,
                         float* __restrict__ out) {
    int b = threadIdx.x;
    if (b < BATCH) out[b] = acc[b] * (1.0f / (float)LEN) + bdec[0];
}

extern "C" void kernel_launch(void* const* d_in, const int* in_sizes, int n_in,
                              void* d_out, int out_size, void* d_ws, size_t ws_size,
                              hipStream_t stream) {
    const float* u          = (const float*)d_in[0];
    const float* log_dt     = (const float*)d_in[1];
    const float* log_A_real = (const float*)d_in[2];
    const float* A_imag     = (const float*)d_in[3];
    const float* B_re       = (const float*)d_in[4];
    const float* B_im       = (const float*)d_in[5];
    const float* C_re       = (const float*)d_in[6];
    const float* C_im       = (const float*)d_in[7];
    const float* Dp         = (const float*)d_in[8];
    const float* W1         = (const float*)d_in[9];
    const float* b1         = (const float*)d_in[10];
    const float* Wdec       = (const float*)d_in[11];
    const float* bdec       = (const float*)d_in[12];
    float* out = (float*)d_out;

    float* w = (float*)d_ws;
    const size_t PN = D_MODEL * D_STATE;          // 8192
    float* dtA_re = w;
    float* dtA_im = dtA_re + PN;
    float* a_re   = dtA_im + PN;
    float* a_im   = a_re + PN;
    float* K      = a_im + PN;                    // 128*1024
    float* pg     = K + (size_t)D_MODEL * LEN;    // 32*128*1024
    float* acc    = pg + (size_t)BATCH * D_MODEL * LEN;  // 32 floats

    k_params<<<D_MODEL, D_STATE, 0, stream>>>(log_dt, log_A_real, A_imag, B_re, B_im,
                                              C_re, C_im, dtA_re, dtA_im, a_re, a_im);
    k_genK<<<dim3(D_MODEL, LEN / 256), 256, 0, stream>>>(dtA_re, dtA_im, a_re, a_im, K);
    k_conv<<<BATCH * D_MODEL, 256, 0, stream>>>(u, K, Dp, pg);
    hipMemsetAsync(acc, 0, BATCH * sizeof(float), stream);
    k_glu<<<BATCH * 16, 256, 0, stream>>>(pg, W1, b1, Wdec, acc);
    k_finish<<<1, 64, 0, stream>>>(acc, bdec, out);
}

// Round 2
// 209.490 us; speedup vs baseline: 1.3012x; 1.3012x over previous
//
#include <hip/hip_runtime.h>
#include <hip/hip_bf16.h>
#include <math.h>

#define D_MODEL 128
#define D_STATE 64
#define LEN 1024
#define BATCH 32

typedef short short8 __attribute__((ext_vector_type(8)));
typedef float f32x4 __attribute__((ext_vector_type(4)));

// ---------------- helpers ----------------
__device__ __forceinline__ float gelu_cheb(float x) {
    float t = (2.0f * x - 10.0f) * 0.05f;   // (2x - (hi+lo)) / (hi-lo), lo=-5 hi=15
    float r = 6.04831644882f + 8.094460228971f * t;
    float tm1 = 1.0f, tc = t;
    float t2 = 2.0f * t * tc - tm1; r += 1.371512430522f  * t2;
    float t3 = 2.0f * t * t2 - tc;  r += -0.740775295685f * t3;
    float t4 = 2.0f * t * t3 - t2;  r += 0.134773988002f  * t4;
    float t5 = 2.0f * t * t4 - t3;  r += 0.126019270103f  * t5;
    float t6 = 2.0f * t * t5 - t4;  r += -0.239569101196f * t6;
    return r;
}

__device__ __forceinline__ unsigned f2bf(float f) {  // f32 -> bf16 bits, RNE
    unsigned u = __float_as_uint(f);
    return (u + 0x7FFFu + ((u >> 16) & 1u)) >> 16;
}

// ---------------- Kernel 1: per-(d,n) S4D parameters ----------------
__global__ void k_params(const float* __restrict__ log_dt, const float* __restrict__ log_A_real,
                         const float* __restrict__ A_imag, const float* __restrict__ B_re,
                         const float* __restrict__ B_im, const float* __restrict__ C_re,
                         const float* __restrict__ C_im,
                         float* __restrict__ dtA_re, float* __restrict__ dtA_im,
                         float* __restrict__ a_re, float* __restrict__ a_im) {
    int d = blockIdx.x;
    int n = threadIdx.x;
    int idx = d * D_STATE + n;
    float dt  = expf(log_dt[d]);
    float Are = -expf(log_A_real[idx]);
    float Aim = A_imag[idx];
    float dre = Are * dt, dim = Aim * dt;
    float e = expf(dre);
    float sn, cs; sincosf(dim, &sn, &cs);
    float Abr = e * cs, Abi = e * sn;
    float numr = Abr - 1.0f, numi = Abi;
    float den = Are * Are + Aim * Aim;
    float inv = 1.0f / den;
    float qr = (numr * Are + numi * Aim) * inv;
    float qi = (numi * Are - numr * Aim) * inv;
    float Br = B_re[idx], Bi = B_im[idx];
    float Bbr = qr * Br - qi * Bi;
    float Bbi = qr * Bi + qi * Br;
    float Cr = C_re[idx], Ci = C_im[idx];
    float ar = Cr * Bbr - Ci * Bbi;
    float ai = Cr * Bbi + Ci * Bbr;
    dtA_re[idx] = dre; dtA_im[idx] = dim;
    a_re[idx] = ar;    a_im[idx] = ai;
}

// ---------------- Kernel 2: K[d][l] = Re( sum_n a_n * exp(dtA_n * l) ) ----------------
__global__ __launch_bounds__(256) void k_genK(const float* __restrict__ dtA_re,
                                              const float* __restrict__ dtA_im,
                                              const float* __restrict__ a_re,
                                              const float* __restrict__ a_im,
                                              float* __restrict__ K) {
    int d = blockIdx.x;
    int l = blockIdx.y * blockDim.x + threadIdx.x;
    float fl = (float)l;
    float acc = 0.0f;
    int base = d * D_STATE;
    for (int n = 0; n < D_STATE; ++n) {
        float e = expf(dtA_re[base + n] * fl);
        float sn, cs; sincosf(dtA_im[base + n] * fl, &sn, &cs);
        acc += e * (a_re[base + n] * cs - a_im[base + n] * sn);
    }
    K[d * LEN + l] = acc;
}

// ---------------- Kernel 3: depthwise conv + skip + GELU poly ----------------
// out[l] = sum_{j=0..l} u[j] * K[j + L-1 - l]; thread t -> outputs l0=4t..4t+3
__global__ __launch_bounds__(256) void k_conv(const float* __restrict__ u,
                                              const float* __restrict__ K,
                                              const float* __restrict__ Dp,
                                              float* __restrict__ pg) {
    __shared__ float u_s[LEN];
    __shared__ float k_s[LEN];
    int b = blockIdx.x >> 7;
    int d = blockIdx.x & 127;
    const float* up = u + (size_t)(b * D_MODEL + d) * LEN;
    const float* kp = K + (size_t)d * LEN;
    int t = threadIdx.x;
    ((float4*)u_s)[t] = ((const float4*)up)[t];
    ((float4*)k_s)[t] = ((const float4*)kp)[t];
    __syncthreads();

    float Dd = Dp[d];
    int l0 = 4 * t;
    int s0 = (LEN - 1) - l0;           // 1023 - 4t
    float acc0 = 0.f, acc1 = 0.f, acc2 = 0.f, acc3 = 0.f;
    float4 kA = *(const float4*)&k_s[s0 - 3];
    for (int J = 0; J < t; ++J) {
        float4 u4 = *(const float4*)&u_s[4 * J];
        float4 kB = *(const float4*)&k_s[4 * J + s0 + 1];
        acc0 += u4.x * kA.w; acc1 += u4.x * kA.z; acc2 += u4.x * kA.y; acc3 += u4.x * kA.x;
        acc0 += u4.y * kB.x; acc1 += u4.y * kA.w; acc2 += u4.y * kA.z; acc3 += u4.y * kA.y;
        acc0 += u4.z * kB.y; acc1 += u4.z * kB.x; acc2 += u4.z * kA.w; acc3 += u4.z * kA.z;
        acc0 += u4.w * kB.z; acc1 += u4.w * kB.y; acc2 += u4.w * kB.x; acc3 += u4.w * kA.w;
        kA = kB;
    }
    float4 u4 = *(const float4*)&u_s[l0];
    acc0 += u4.x * kA.w;
    acc1 += u4.x * kA.z + u4.y * kA.w;
    acc2 += u4.x * kA.y + u4.y * kA.z + u4.z * kA.w;
    acc3 += u4.x * kA.x + u4.y * kA.y + u4.z * kA.z + u4.w * kA.w;

    float4 outv;
    outv.x = gelu_cheb(acc0 + u4.x * Dd);
    outv.y = gelu_cheb(acc1 + u4.y * Dd);
    outv.z = gelu_cheb(acc2 + u4.z * Dd);
    outv.w = gelu_cheb(acc3 + u4.w * Dd);
    ((float4*)(pg + (size_t)(b * D_MODEL + d) * LEN))[t] = outv;
}

// ---------------- Kernel 3b: W1 f32 -> bf16 ----------------
__global__ void k_cvt(const float* __restrict__ W1, short* __restrict__ w1bf) {
    int i = blockIdx.x * 256 + threadIdx.x;   // 32768 total
    w1bf[i] = (short)f2bf(W1[i]);
}

// ---------------- Kernel 4: MFMA GEMM + GLU gate + pooling epilogue ----------------
// C[o, l] = sum_k W1[o,k] * pg[b,k,l]; block = (l-chunk of 64, b); 4 waves.
// Wave w owns o rows [32w,32w+32) ("a") and [128+32w, 128+32w+32) ("b") so the
// gate pair (o, o+128) sits in the same lane/register.
#define XS_STRIDE 136   // 64-l rows of 128 k bf16, padded to 136 (272 B, 16B-aligned rows)
__global__ __launch_bounds__(256) void k_glu_mfma(const float* __restrict__ pg,
                                                  const short* __restrict__ w1bf,
                                                  const float* __restrict__ b1,
                                                  const float* __restrict__ Wdec,
                                                  float* __restrict__ acc) {
    __shared__ __align__(16) short xs[64 * XS_STRIDE];
    int b = blockIdx.y;
    int l0 = blockIdx.x * 64;
    int t = threadIdx.x;

    // ---- stage pg[b, :, l0:l0+64] into xs[l][k] (bf16, transposed) ----
    {
        int l = t & 63, k2 = t >> 6;                 // wave-uniform k2
        const float* pgb = pg + (size_t)b * D_MODEL * LEN + l0 + l;
#pragma unroll
        for (int i = 0; i < 16; ++i) {
            int k = 2 * (k2 + 4 * i);                // even k, covers 0..127 once
            float f0 = pgb[(size_t)k * LEN];
            float f1 = pgb[(size_t)(k + 1) * LEN];
            unsigned pack = f2bf(f0) | (f2bf(f1) << 16);
            *(unsigned*)&xs[l * XS_STRIDE + k] = pack;
        }
    }
    __syncthreads();

    int wv = t >> 6, lane = t & 63;
    int m = lane & 15, q = lane >> 4;                // A/B frag: element m, k-quad q

    f32x4 accA[2][4], accB[2][4];
#pragma unroll
    for (int p = 0; p < 2; ++p)
#pragma unroll
        for (int nt = 0; nt < 4; ++nt) {
            accA[p][nt] = (f32x4){0.f, 0.f, 0.f, 0.f};
            accB[p][nt] = (f32x4){0.f, 0.f, 0.f, 0.f};
        }

    const short* wA0 = w1bf + ((2 * wv + 0) * 16 + m) * D_MODEL;
    const short* wA1 = w1bf + ((2 * wv + 1) * 16 + m) * D_MODEL;

#pragma unroll
    for (int kk = 0; kk < 128; kk += 32) {
        int ko = kk + q * 8;
        short8 bfr[4];
#pragma unroll
        for (int nt = 0; nt < 4; ++nt)
            bfr[nt] = *(const short8*)&xs[(nt * 16 + m) * XS_STRIDE + ko];
        short8 aA0 = *(const short8*)(wA0 + ko);
        short8 aA1 = *(const short8*)(wA1 + ko);
        short8 aB0 = *(const short8*)(wA0 + 128 * D_MODEL + ko);
        short8 aB1 = *(const short8*)(wA1 + 128 * D_MODEL + ko);
#pragma unroll
        for (int nt = 0; nt < 4; ++nt) {
            accA[0][nt] = __builtin_amdgcn_mfma_f32_16x16x32_bf16(aA0, bfr[nt], accA[0][nt], 0, 0, 0);
            accA[1][nt] = __builtin_amdgcn_mfma_f32_16x16x32_bf16(aA1, bfr[nt], accA[1][nt], 0, 0, 0);
            accB[0][nt] = __builtin_amdgcn_mfma_f32_16x16x32_bf16(aB0, bfr[nt], accB[0][nt], 0, 0, 0);
            accB[1][nt] = __builtin_amdgcn_mfma_f32_16x16x32_bf16(aB1, bfr[nt], accB[1][nt], 0, 0, 0);
        }
    }

    // ---- epilogue: bias, gate, Wdec, pool ----
    float s = 0.f;
#pragma unroll
    for (int p = 0; p < 2; ++p) {
        int oA = (2 * wv + p) * 16 + q * 4;          // C row = q*4 + r
#pragma unroll
        for (int r = 0; r < 4; ++r) {
            int o = oA + r;
            float wd  = Wdec[o];
            float ba  = b1[o];
            float bb1 = b1[o + 128];
#pragma unroll
            for (int nt = 0; nt < 4; ++nt) {
                float aa  = accA[p][nt][r] + ba;
                float bbv = accB[p][nt][r] + bb1;
                float g = fminf(fmaxf(0.25f * bbv + 0.5f, 0.f), 1.f);
                s += wd * aa * g;
            }
        }
    }
#pragma unroll
    for (int off = 32; off > 0; off >>= 1) s += __shfl_down(s, off, 64);
    if (lane == 0) atomicAdd(&acc[b], s);
}

// ---------------- Kernel 5: finalize ----------------
__global__ void k_finish(const float* __restrict__ acc, const float* __restrict__ bdec,
                         float* __restrict__ out) {
    int b = threadIdx.x;
    if (b < BATCH) out[b] = acc[b] * (1.0f / (float)LEN) + bdec[0];
}

extern "C" void kernel_launch(void* const* d_in, const int* in_sizes, int n_in,
                              void* d_out, int out_size, void* d_ws, size_t ws_size,
                              hipStream_t stream) {
    const float* u          = (const float*)d_in[0];
    const float* log_dt     = (const float*)d_in[1];
    const float* log_A_real = (const float*)d_in[2];
    const float* A_imag     = (const float*)d_in[3];
    const float* B_re       = (const float*)d_in[4];
    const float* B_im       = (const float*)d_in[5];
    const float* C_re       = (const float*)d_in[6];
    const float* C_im       = (const float*)d_in[7];
    const float* Dp         = (const float*)d_in[8];
    const float* W1         = (const float*)d_in[9];
    const float* b1         = (const float*)d_in[10];
    const float* Wdec       = (const float*)d_in[11];
    const float* bdec       = (const float*)d_in[12];
    float* out = (float*)d_out;

    float* w = (float*)d_ws;
    const size_t PN = D_MODEL * D_STATE;          // 8192
    float* dtA_re = w;
    float* dtA_im = dtA_re + PN;
    float* a_re   = dtA_im + PN;
    float* a_im   = a_re + PN;
    float* K      = a_im + PN;                    // 128*1024
    float* pg     = K + (size_t)D_MODEL * LEN;    // 32*128*1024
    float* acc    = pg + (size_t)BATCH * D_MODEL * LEN;  // 32 floats
    short* w1bf   = (short*)(acc + 64);           // 256*128 bf16

    k_params<<<D_MODEL, D_STATE, 0, stream>>>(log_dt, log_A_real, A_imag, B_re, B_im,
                                              C_re, C_im, dtA_re, dtA_im, a_re, a_im);
    k_genK<<<dim3(D_MODEL, LEN / 256), 256, 0, stream>>>(dtA_re, dtA_im, a_re, a_im, K);
    k_conv<<<BATCH * D_MODEL, 256, 0, stream>>>(u, K, Dp, pg);
    k_cvt<<<D_MODEL * 2 * D_MODEL / 256, 256, 0, stream>>>(W1, w1bf);
    hipMemsetAsync(acc, 0, BATCH * sizeof(float), stream);
    k_glu_mfma<<<dim3(LEN / 64, BATCH), 256, 0, stream>>>(pg, w1bf, b1, Wdec, acc);
    k_finish<<<1, 64, 0, stream>>>(acc, bdec, out);
}

// Round 3
// 189.708 us; speedup vs baseline: 1.4369x; 1.1043x over previous
//
#include <hip/hip_runtime.h>
#include <hip/hip_bf16.h>
#include <math.h>

#define D_MODEL 128
#define D_STATE 64
#define LEN 1024
#define BATCH 32

typedef short short8 __attribute__((ext_vector_type(8)));
typedef float f32x4 __attribute__((ext_vector_type(4)));

// ---------------- helpers ----------------
__device__ __forceinline__ float gelu_cheb(float x) {
    float t = (2.0f * x - 10.0f) * 0.05f;   // (2x - (hi+lo)) / (hi-lo), lo=-5 hi=15
    float r = 6.04831644882f + 8.094460228971f * t;
    float tm1 = 1.0f, tc = t;
    float t2 = 2.0f * t * tc - tm1; r += 1.371512430522f  * t2;
    float t3 = 2.0f * t * t2 - tc;  r += -0.740775295685f * t3;
    float t4 = 2.0f * t * t3 - t2;  r += 0.134773988002f  * t4;
    float t5 = 2.0f * t * t4 - t3;  r += 0.126019270103f  * t5;
    float t6 = 2.0f * t * t5 - t4;  r += -0.239569101196f * t6;
    return r;
}

__device__ __forceinline__ unsigned f2bf(float f) {  // f32 -> bf16 bits, RNE
    unsigned u = __float_as_uint(f);
    return (u + 0x7FFFu + ((u >> 16) & 1u)) >> 16;
}

// ---------------- Kernel 1: per-(d,n) S4D parameters ----------------
__global__ void k_params(const float* __restrict__ log_dt, const float* __restrict__ log_A_real,
                         const float* __restrict__ A_imag, const float* __restrict__ B_re,
                         const float* __restrict__ B_im, const float* __restrict__ C_re,
                         const float* __restrict__ C_im,
                         float* __restrict__ dtA_re, float* __restrict__ dtA_im,
                         float* __restrict__ a_re, float* __restrict__ a_im) {
    int d = blockIdx.x;
    int n = threadIdx.x;
    int idx = d * D_STATE + n;
    float dt  = expf(log_dt[d]);
    float Are = -expf(log_A_real[idx]);
    float Aim = A_imag[idx];
    float dre = Are * dt, dim = Aim * dt;
    float e = expf(dre);
    float sn, cs; sincosf(dim, &sn, &cs);
    float Abr = e * cs, Abi = e * sn;
    float numr = Abr - 1.0f, numi = Abi;
    float den = Are * Are + Aim * Aim;
    float inv = 1.0f / den;
    float qr = (numr * Are + numi * Aim) * inv;
    float qi = (numi * Are - numr * Aim) * inv;
    float Br = B_re[idx], Bi = B_im[idx];
    float Bbr = qr * Br - qi * Bi;
    float Bbi = qr * Bi + qi * Br;
    float Cr = C_re[idx], Ci = C_im[idx];
    float ar = Cr * Bbr - Ci * Bbi;
    float ai = Cr * Bbi + Ci * Bbr;
    dtA_re[idx] = dre; dtA_im[idx] = dim;
    a_re[idx] = ar;    a_im[idx] = ai;
}

// ---------------- Kernel 2: K[d][l] = Re( sum_n a_n * exp(dtA_n * l) ) ----------------
__global__ __launch_bounds__(256) void k_genK(const float* __restrict__ dtA_re,
                                              const float* __restrict__ dtA_im,
                                              const float* __restrict__ a_re,
                                              const float* __restrict__ a_im,
                                              float* __restrict__ K) {
    int d = blockIdx.x;
    int l = blockIdx.y * blockDim.x + threadIdx.x;
    float fl = (float)l;
    float acc = 0.0f;
    int base = d * D_STATE;
    for (int n = 0; n < D_STATE; ++n) {
        float e = expf(dtA_re[base + n] * fl);
        float sn, cs; sincosf(dtA_im[base + n] * fl, &sn, &cs);
        acc += e * (a_re[base + n] * cs - a_im[base + n] * sn);
    }
    K[d * LEN + l] = acc;
}

// ---------------- Kernel 3: Toeplitz MFMA conv + skip + GELU ----------------
// out[b,d,l] = sum_j u[b,d,j] * Kp[1023 + j - l], Kp zero-padded above 1023.
// Tile: C (16 l x 16 b) = T (16 l x 32 j) @ U (32 j x 16 b) via mfma 16x16x32.
// A-frag lane reads 8 CONSECUTIVE Kp elems -> 16B LDS read from one of 8
// shift-by-1 copies (alignment). Block = (d, batch-half nh, I-parity s).
// Wave w owns I-tiles I = 2*(w+4j)+s, j=0..7 (balanced). Epilogue fuses
// skip (f32 u), GELU, bf16 cast; stores pgT[b][l][d].
__global__ __launch_bounds__(256) void k_conv_mfma(const float* __restrict__ u,
                                                   const float* __restrict__ K,
                                                   const float* __restrict__ Dp,
                                                   short* __restrict__ pgT) {
    __shared__ __align__(16) short Kc[8][1096];   // Kc[c][x] = bf16(Kp[x+c]); stride 2192B
    __shared__ __align__(16) short Us[16][1032];  // Us[n][j] = bf16(u[b0+n,d,j]); stride 2064B
    int bid = blockIdx.x;
    int d  = bid >> 2;
    int nh = (bid >> 1) & 1;
    int s  = bid & 1;
    int t = threadIdx.x;

    // zero Kc (covers the j>l zero pad and copy tails)
    short* kcf = &Kc[0][0];
    for (int i = t; i < 8 * 1096; i += 256) kcf[i] = 0;

    // stage Us: row r = batch (within half), 64 floats per thread
    {
        int r = t >> 4;
        int c0 = (t & 15) * 64;
        const float* up = u + ((size_t)(nh * 16 + r) * D_MODEL + d) * LEN;
#pragma unroll
        for (int i = 0; i < 8; ++i) {
            float4 va = *(const float4*)&up[c0 + 8 * i];
            float4 vb = *(const float4*)&up[c0 + 8 * i + 4];
            short8 w;
            w[0] = (short)f2bf(va.x); w[1] = (short)f2bf(va.y);
            w[2] = (short)f2bf(va.z); w[3] = (short)f2bf(va.w);
            w[4] = (short)f2bf(vb.x); w[5] = (short)f2bf(vb.y);
            w[6] = (short)f2bf(vb.z); w[7] = (short)f2bf(vb.w);
            *(short8*)&Us[r][c0 + 8 * i] = w;
        }
    }
    __syncthreads();

    // scatter K -> 8 shifted copies (after zero-fill barrier)
    {
        float4 kv = ((const float4*)(K + (size_t)d * LEN))[t];
        float vals[4] = {kv.x, kv.y, kv.z, kv.w};
#pragma unroll
        for (int mm = 0; mm < 4; ++mm) {
            int e = 4 * t + mm;
            short bv = (short)f2bf(vals[mm]);
#pragma unroll
            for (int c = 0; c < 8; ++c) {
                int x = e - c;
                if (x >= 0) Kc[c][x] = bv;
            }
        }
    }
    __syncthreads();

    int wv = t >> 6, lane = t & 63;
    int m16 = lane & 15, q = lane >> 4;

    f32x4 acc[8];
#pragma unroll
    for (int j = 0; j < 8; ++j) acc[j] = (f32x4){0.f, 0.f, 0.f, 0.f};

    for (int ks = 0; ks < 32; ++ks) {
        short8 bfrag = *(const short8*)&Us[m16][ks * 32 + q * 8];
#pragma unroll
        for (int j = 0; j < 8; ++j) {
            int halfI = wv + 4 * j;                  // floor(I/2), wave-uniform guard
            if (halfI >= ks) {
                int I = 2 * halfI + s;
                int base = 1023 + 32 * ks + 8 * q - 16 * I - m16;
                int c = base & 7;
                short8 afrag = *(const short8*)&Kc[c][base - c];
                acc[j] = __builtin_amdgcn_mfma_f32_16x16x32_bf16(afrag, bfrag, acc[j], 0, 0, 0);
            }
        }
    }

    // epilogue: C col = lane&15 = batch, row = 4q+r = l offset in tile
    float Dd = Dp[d];
    int b = nh * 16 + m16;
    const float* ug = u + ((size_t)b * D_MODEL + d) * LEN;
#pragma unroll
    for (int j = 0; j < 8; ++j) {
        int I = 2 * (wv + 4 * j) + s;
        int l0 = 16 * I + 4 * q;
        float4 u4 = *(const float4*)&ug[l0];
        float v0 = gelu_cheb(acc[j][0] + u4.x * Dd);
        float v1 = gelu_cheb(acc[j][1] + u4.y * Dd);
        float v2 = gelu_cheb(acc[j][2] + u4.z * Dd);
        float v3 = gelu_cheb(acc[j][3] + u4.w * Dd);
        size_t base = ((size_t)b * LEN + l0) * D_MODEL + d;
        pgT[base + 0 * D_MODEL] = (short)f2bf(v0);
        pgT[base + 1 * D_MODEL] = (short)f2bf(v1);
        pgT[base + 2 * D_MODEL] = (short)f2bf(v2);
        pgT[base + 3 * D_MODEL] = (short)f2bf(v3);
    }
}

// ---------------- Kernel 3b: W1 f32 -> bf16 ----------------
__global__ void k_cvt(const float* __restrict__ W1, short* __restrict__ w1bf) {
    int i = blockIdx.x * 256 + threadIdx.x;   // 32768 total
    w1bf[i] = (short)f2bf(W1[i]);
}

// ---------------- Kernel 4: MFMA GEMM + GLU gate + pooling epilogue ----------------
// C[o, l] = sum_k W1[o,k] * pgT[b,l,k]; B-frags read directly from global
// (contiguous 16B per lane in pgT layout). No LDS, no barrier.
__global__ __launch_bounds__(256) void k_glu_mfma(const short* __restrict__ pgT,
                                                  const short* __restrict__ w1bf,
                                                  const float* __restrict__ b1,
                                                  const float* __restrict__ Wdec,
                                                  float* __restrict__ acc) {
    int b = blockIdx.y;
    int l0 = blockIdx.x * 64;
    int t = threadIdx.x;
    int wv = t >> 6, lane = t & 63;
    int m = lane & 15, q = lane >> 4;

    f32x4 accA[2][4], accB[2][4];
#pragma unroll
    for (int p = 0; p < 2; ++p)
#pragma unroll
        for (int nt = 0; nt < 4; ++nt) {
            accA[p][nt] = (f32x4){0.f, 0.f, 0.f, 0.f};
            accB[p][nt] = (f32x4){0.f, 0.f, 0.f, 0.f};
        }

    const short* wA0 = w1bf + ((2 * wv + 0) * 16 + m) * D_MODEL;
    const short* wA1 = w1bf + ((2 * wv + 1) * 16 + m) * D_MODEL;
    const short* pgb = pgT + ((size_t)b * LEN + l0) * D_MODEL;

#pragma unroll
    for (int kk = 0; kk < 128; kk += 32) {
        int ko = kk + q * 8;
        short8 bfr[4];
#pragma unroll
        for (int nt = 0; nt < 4; ++nt)
            bfr[nt] = *(const short8*)&pgb[(size_t)(nt * 16 + m) * D_MODEL + ko];
        short8 aA0 = *(const short8*)(wA0 + ko);
        short8 aA1 = *(const short8*)(wA1 + ko);
        short8 aB0 = *(const short8*)(wA0 + 128 * D_MODEL + ko);
        short8 aB1 = *(const short8*)(wA1 + 128 * D_MODEL + ko);
#pragma unroll
        for (int nt = 0; nt < 4; ++nt) {
            accA[0][nt] = __builtin_amdgcn_mfma_f32_16x16x32_bf16(aA0, bfr[nt], accA[0][nt], 0, 0, 0);
            accA[1][nt] = __builtin_amdgcn_mfma_f32_16x16x32_bf16(aA1, bfr[nt], accA[1][nt], 0, 0, 0);
            accB[0][nt] = __builtin_amdgcn_mfma_f32_16x16x32_bf16(aB0, bfr[nt], accB[0][nt], 0, 0, 0);
            accB[1][nt] = __builtin_amdgcn_mfma_f32_16x16x32_bf16(aB1, bfr[nt], accB[1][nt], 0, 0, 0);
        }
    }

    float s = 0.f;
#pragma unroll
    for (int p = 0; p < 2; ++p) {
        int oA = (2 * wv + p) * 16 + q * 4;
#pragma unroll
        for (int r = 0; r < 4; ++r) {
            int o = oA + r;
            float wd  = Wdec[o];
            float ba  = b1[o];
            float bb1 = b1[o + 128];
#pragma unroll
            for (int nt = 0; nt < 4; ++nt) {
                float aa  = accA[p][nt][r] + ba;
                float bbv = accB[p][nt][r] + bb1;
                float g = fminf(fmaxf(0.25f * bbv + 0.5f, 0.f), 1.f);
                s += wd * aa * g;
            }
        }
    }
#pragma unroll
    for (int off = 32; off > 0; off >>= 1) s += __shfl_down(s, off, 64);
    if (lane == 0) atomicAdd(&acc[b], s);
}

// ---------------- Kernel 5: finalize ----------------
__global__ void k_finish(const float* __restrict__ acc, const float* __restrict__ bdec,
                         float* __restrict__ out) {
    int b = threadIdx.x;
    if (b < BATCH) out[b] = acc[b] * (1.0f / (float)LEN) + bdec[0];
}

extern "C" void kernel_launch(void* const* d_in, const int* in_sizes, int n_in,
                              void* d_out, int out_size, void* d_ws, size_t ws_size,
                              hipStream_t stream) {
    const float* u          = (const float*)d_in[0];
    const float* log_dt     = (const float*)d_in[1];
    const float* log_A_real = (const float*)d_in[2];
    const float* A_imag     = (const float*)d_in[3];
    const float* B_re       = (const float*)d_in[4];
    const float* B_im       = (const float*)d_in[5];
    const float* C_re       = (const float*)d_in[6];
    const float* C_im       = (const float*)d_in[7];
    const float* Dp         = (const float*)d_in[8];
    const float* W1         = (const float*)d_in[9];
    const float* b1         = (const float*)d_in[10];
    const float* Wdec       = (const float*)d_in[11];
    const float* bdec       = (const float*)d_in[12];
    float* out = (float*)d_out;

    float* w = (float*)d_ws;
    const size_t PN = D_MODEL * D_STATE;          // 8192
    float* dtA_re = w;
    float* dtA_im = dtA_re + PN;
    float* a_re   = dtA_im + PN;
    float* a_im   = a_re + PN;
    float* K      = a_im + PN;                    // 128*1024 f32
    float* acc    = K + (size_t)D_MODEL * LEN;    // 32 floats (+pad to 64)
    short* pgT    = (short*)(acc + 64);           // [b][l][d] bf16: 32*1024*128
    short* w1bf   = pgT + (size_t)BATCH * LEN * D_MODEL;  // 256*128 bf16

    k_params<<<D_MODEL, D_STATE, 0, stream>>>(log_dt, log_A_real, A_imag, B_re, B_im,
                                              C_re, C_im, dtA_re, dtA_im, a_re, a_im);
    k_genK<<<dim3(D_MODEL, LEN / 256), 256, 0, stream>>>(dtA_re, dtA_im, a_re, a_im, K);
    k_cvt<<<D_MODEL * 2 * D_MODEL / 256, 256, 0, stream>>>(W1, w1bf);
    k_conv_mfma<<<D_MODEL * 4, 256, 0, stream>>>(u, K, Dp, pgT);
    hipMemsetAsync(acc, 0, BATCH * sizeof(float), stream);
    k_glu_mfma<<<dim3(LEN / 64, BATCH), 256, 0, stream>>>(pgT, w1bf, b1, Wdec, acc);
    k_finish<<<1, 64, 0, stream>>>(acc, bdec, out);
}

// Round 4
// 181.742 us; speedup vs baseline: 1.4998x; 1.0438x over previous
//
#include <hip/hip_runtime.h>
#include <hip/hip_bf16.h>
#include <math.h>

#define D_MODEL 128
#define D_STATE 64
#define LEN 1024
#define BATCH 32

typedef short short8 __attribute__((ext_vector_type(8)));
typedef float f32x4 __attribute__((ext_vector_type(4)));

union PackU { uint4 u; short8 s; };

// ---------------- helpers ----------------
__device__ __forceinline__ float gelu_cheb(float x) {
    float t = (2.0f * x - 10.0f) * 0.05f;   // (2x - (hi+lo)) / (hi-lo), lo=-5 hi=15
    float r = 6.04831644882f + 8.094460228971f * t;
    float tm1 = 1.0f, tc = t;
    float t2 = 2.0f * t * tc - tm1; r += 1.371512430522f  * t2;
    float t3 = 2.0f * t * t2 - tc;  r += -0.740775295685f * t3;
    float t4 = 2.0f * t * t3 - t2;  r += 0.134773988002f  * t4;
    float t5 = 2.0f * t * t4 - t3;  r += 0.126019270103f  * t5;
    float t6 = 2.0f * t * t5 - t4;  r += -0.239569101196f * t6;
    return r;
}

__device__ __forceinline__ unsigned f2bf(float f) {  // f32 -> bf16 bits, RNE
    unsigned u = __float_as_uint(f);
    return (u + 0x7FFFu + ((u >> 16) & 1u)) >> 16;
}

// ---------------- Kernel 1: fused params + K via chunked recurrence ----------------
// K[d][l] = Re( sum_n a_n * z_n^l ), z = exp(dtA). Chunk of 32 l per wave:
// exact expf/sincosf start at l0, then 32 complex-mul steps (drift ~32*1e-7).
// Large angles only occur where exp(dre*l) ~ e^-20 -> contribution dead.
// Cross-n sum: 6-step __shfl_xor butterfly (lane = n).
// Fused side jobs: W1 -> bf16 convert (32 elems/block), acc zero (block 0).
__global__ __launch_bounds__(256) void k_genK2(const float* __restrict__ log_dt,
                                               const float* __restrict__ log_A_real,
                                               const float* __restrict__ A_imag,
                                               const float* __restrict__ B_re,
                                               const float* __restrict__ B_im,
                                               const float* __restrict__ C_re,
                                               const float* __restrict__ C_im,
                                               const float* __restrict__ W1,
                                               short* __restrict__ w1bf,
                                               float* __restrict__ K,
                                               float* __restrict__ acc) {
    int bid = blockIdx.x;             // 1024 = 128 d * 8 oct
    int d = bid >> 3, oct = bid & 7;
    int t = threadIdx.x;

    if (t < 32) { int i = bid * 32 + t; w1bf[i] = (short)f2bf(W1[i]); }
    if (bid == 0 && t >= 32 && t < 96) acc[t - 32] = 0.f;

    int w = t >> 6, lane = t & 63;
    int idx = d * D_STATE + lane;
    float dt  = expf(log_dt[d]);
    float Are = -expf(log_A_real[idx]);
    float Aim = A_imag[idx];
    float dre = Are * dt, dim = Aim * dt;
    // a = Cc * B_bar, B_bar = (A_bar-1)/A * Bc
    float e = expf(dre);
    float sn, cs; sincosf(dim, &sn, &cs);
    float zre = e * cs, zim = e * sn;                 // z = A_bar
    float numr = zre - 1.0f, numi = zim;
    float inv = 1.0f / (Are * Are + Aim * Aim);
    float qr = (numr * Are + numi * Aim) * inv;
    float qi = (numi * Are - numr * Aim) * inv;
    float Br = B_re[idx], Bi = B_im[idx];
    float Bbr = qr * Br - qi * Bi;
    float Bbi = qr * Bi + qi * Br;
    float Cr = C_re[idx], Ci = C_im[idx];
    float ar = Cr * Bbr - Ci * Bbi;
    float ai = Cr * Bbi + Ci * Bbr;

    int c = oct * 4 + w;
    int l0 = 32 * c;
    float fl0 = (float)l0;
    float pre = 0.f, pim = 0.f;
    if (dre * fl0 > -20.f) {                          // alive at chunk start
        float e0 = expf(dre * fl0);
        float s0, c0; sincosf(dim * fl0, &s0, &c0);
        pre = e0 * (ar * c0 - ai * s0);
        pim = e0 * (ar * s0 + ai * c0);
    }

    float kept = 0.f;
#pragma unroll
    for (int r = 0; r < 32; ++r) {
        float s = pre;
#pragma unroll
        for (int mm = 1; mm < 64; mm <<= 1) s += __shfl_xor(s, mm, 64);
        if (lane == r) kept = s;
        float nre = pre * zre - pim * zim;
        pim = pre * zim + pim * zre;
        pre = nre;
    }
    if (lane < 32) K[(size_t)d * LEN + l0 + lane] = kept;
}

// ---------------- Kernel 2: dense Toeplitz MFMA conv + skip + GELU ----------------
// out[b,d,l] = sum_j u[b,d,j] * Kp[1023 + j - l], Kp zero above 1023 (dense k-loop,
// upper triangle reads zeros). A-frag start s = 1023+32ks+8q-16I-m16 has fixed
// parity per lane -> 2 dword-pair copies P0[y]=(e2y,e2y+1), P1[y]=(e2y+1,e2y+2);
// y = s>>1 indexes either; 4 ds_read_b32 at immediate offsets per frag.
// Block = (d, nh batch-half, sq = I mod 4); wave w owns I = sq + 4*(w + 4j), j=0..3.
#define US_STRIDE 1032
__global__ __launch_bounds__(256) void k_conv2(const float* __restrict__ u,
                                               const float* __restrict__ K,
                                               const float* __restrict__ Dp,
                                               short* __restrict__ pgT) {
    __shared__ unsigned P[2][1027];               // [0]=even-start copy, [1]=odd
    __shared__ __align__(16) short Us[16][US_STRIDE];
    int bid = blockIdx.x;                         // 128 d * 2 nh * 4 sq
    int d  = bid >> 3;
    int nh = (bid >> 2) & 1;
    int sq = bid & 3;
    int t = threadIdx.x;

    // zero pad region (elements >= 1024 read as 0)
    for (int y = 512 + t; y < 1027; y += 256) { P[0][y] = 0u; P[1][y] = 0u; }

    // fill P0/P1 from K[d]
    {
        const float* kp = K + (size_t)d * LEN;
        float4 kv = ((const float4*)kp)[t];
        unsigned e0 = f2bf(kv.x), e1 = f2bf(kv.y), e2 = f2bf(kv.z), e3 = f2bf(kv.w);
        unsigned e4 = (t < 255) ? f2bf(kp[4 * t + 4]) : 0u;
        P[0][2 * t]     = e0 | (e1 << 16);
        P[0][2 * t + 1] = e2 | (e3 << 16);
        P[1][2 * t]     = e1 | (e2 << 16);
        P[1][2 * t + 1] = e3 | (e4 << 16);
    }

    // stage Us[b][j] bf16
    {
        int r = t >> 4, c0 = (t & 15) * 64;
        const float* up = u + ((size_t)(nh * 16 + r) * D_MODEL + d) * LEN;
#pragma unroll
        for (int i = 0; i < 8; ++i) {
            float4 va = *(const float4*)&up[c0 + 8 * i];
            float4 vb = *(const float4*)&up[c0 + 8 * i + 4];
            short8 wv;
            wv[0] = (short)f2bf(va.x); wv[1] = (short)f2bf(va.y);
            wv[2] = (short)f2bf(va.z); wv[3] = (short)f2bf(va.w);
            wv[4] = (short)f2bf(vb.x); wv[5] = (short)f2bf(vb.y);
            wv[6] = (short)f2bf(vb.z); wv[7] = (short)f2bf(vb.w);
            *(short8*)&Us[r][c0 + 8 * i] = wv;
        }
    }
    __syncthreads();

    int wv_ = t >> 6, lane = t & 63;
    int m16 = lane & 15, q = lane >> 4;
    const unsigned* Pc = (m16 & 1) ? &P[0][0] : &P[1][0];   // odd m16 -> s even -> P0

    unsigned y0[4];
    f32x4 accv[4];
#pragma unroll
    for (int j = 0; j < 4; ++j) {
        int I = sq + 4 * (wv_ + 4 * j);
        int S0 = 1023 + 8 * q - 16 * I - m16;     // >= 0
        y0[j] = ((unsigned)S0) >> 1;
        accv[j] = (f32x4){0.f, 0.f, 0.f, 0.f};
    }

#pragma unroll
    for (int ks = 0; ks < 32; ++ks) {
        short8 bfrag = *(const short8*)&Us[m16][32 * ks + 8 * q];
#pragma unroll
        for (int j = 0; j < 4; ++j) {
            unsigned y = y0[j] + 16 * ks;
            PackU pu;
            pu.u.x = Pc[y]; pu.u.y = Pc[y + 1]; pu.u.z = Pc[y + 2]; pu.u.w = Pc[y + 3];
            accv[j] = __builtin_amdgcn_mfma_f32_16x16x32_bf16(pu.s, bfrag, accv[j], 0, 0, 0);
        }
    }

    // epilogue: C col = m16 = batch-in-half, row = 4q+r = l offset in tile
    float Dd = Dp[d];
    int b = nh * 16 + m16;
    const float* ug = u + ((size_t)b * D_MODEL + d) * LEN;
#pragma unroll
    for (int j = 0; j < 4; ++j) {
        int I = sq + 4 * (wv_ + 4 * j);
        int l0 = 16 * I + 4 * q;
        float4 u4 = *(const float4*)&ug[l0];
        float v0 = gelu_cheb(accv[j][0] + u4.x * Dd);
        float v1 = gelu_cheb(accv[j][1] + u4.y * Dd);
        float v2 = gelu_cheb(accv[j][2] + u4.z * Dd);
        float v3 = gelu_cheb(accv[j][3] + u4.w * Dd);
        size_t base = ((size_t)b * LEN + l0) * D_MODEL + d;
        pgT[base + 0 * D_MODEL] = (short)f2bf(v0);
        pgT[base + 1 * D_MODEL] = (short)f2bf(v1);
        pgT[base + 2 * D_MODEL] = (short)f2bf(v2);
        pgT[base + 3 * D_MODEL] = (short)f2bf(v3);
    }
}

// ---------------- Kernel 3: MFMA GEMM + GLU gate + pooling epilogue ----------------
// C[o, l] = sum_k W1[o,k] * pgT[b,l,k]; 32-l tiles, 1024 blocks, B-frags direct
// from global (contiguous 16B per lane). No LDS, no barrier.
__global__ __launch_bounds__(256) void k_glu_mfma(const short* __restrict__ pgT,
                                                  const short* __restrict__ w1bf,
                                                  const float* __restrict__ b1,
                                                  const float* __restrict__ Wdec,
                                                  float* __restrict__ acc) {
    int b = blockIdx.y;
    int l0 = blockIdx.x * 32;
    int t = threadIdx.x;
    int wv = t >> 6, lane = t & 63;
    int m = lane & 15, q = lane >> 4;

    f32x4 accA[2][2], accB[2][2];
#pragma unroll
    for (int p = 0; p < 2; ++p)
#pragma unroll
        for (int nt = 0; nt < 2; ++nt) {
            accA[p][nt] = (f32x4){0.f, 0.f, 0.f, 0.f};
            accB[p][nt] = (f32x4){0.f, 0.f, 0.f, 0.f};
        }

    const short* wA0 = w1bf + ((2 * wv + 0) * 16 + m) * D_MODEL;
    const short* wA1 = w1bf + ((2 * wv + 1) * 16 + m) * D_MODEL;
    const short* pgb = pgT + ((size_t)b * LEN + l0) * D_MODEL;

#pragma unroll
    for (int kk = 0; kk < 128; kk += 32) {
        int ko = kk + q * 8;
        short8 bfr[2];
#pragma unroll
        for (int nt = 0; nt < 2; ++nt)
            bfr[nt] = *(const short8*)&pgb[(size_t)(nt * 16 + m) * D_MODEL + ko];
        short8 aA0 = *(const short8*)(wA0 + ko);
        short8 aA1 = *(const short8*)(wA1 + ko);
        short8 aB0 = *(const short8*)(wA0 + 128 * D_MODEL + ko);
        short8 aB1 = *(const short8*)(wA1 + 128 * D_MODEL + ko);
#pragma unroll
        for (int nt = 0; nt < 2; ++nt) {
            accA[0][nt] = __builtin_amdgcn_mfma_f32_16x16x32_bf16(aA0, bfr[nt], accA[0][nt], 0, 0, 0);
            accA[1][nt] = __builtin_amdgcn_mfma_f32_16x16x32_bf16(aA1, bfr[nt], accA[1][nt], 0, 0, 0);
            accB[0][nt] = __builtin_amdgcn_mfma_f32_16x16x32_bf16(aB0, bfr[nt], accB[0][nt], 0, 0, 0);
            accB[1][nt] = __builtin_amdgcn_mfma_f32_16x16x32_bf16(aB1, bfr[nt], accB[1][nt], 0, 0, 0);
        }
    }

    float s = 0.f;
#pragma unroll
    for (int p = 0; p < 2; ++p) {
        int oA = (2 * wv + p) * 16 + q * 4;
#pragma unroll
        for (int r = 0; r < 4; ++r) {
            int o = oA + r;
            float wd  = Wdec[o];
            float ba  = b1[o];
            float bb1 = b1[o + 128];
#pragma unroll
            for (int nt = 0; nt < 2; ++nt) {
                float aa  = accA[p][nt][r] + ba;
                float bbv = accB[p][nt][r] + bb1;
                float g = fminf(fmaxf(0.25f * bbv + 0.5f, 0.f), 1.f);
                s += wd * aa * g;
            }
        }
    }
#pragma unroll
    for (int off = 32; off > 0; off >>= 1) s += __shfl_down(s, off, 64);
    if (lane == 0) atomicAdd(&acc[b], s);
}

// ---------------- Kernel 4: finalize ----------------
__global__ void k_finish(const float* __restrict__ acc, const float* __restrict__ bdec,
                         float* __restrict__ out) {
    int b = threadIdx.x;
    if (b < BATCH) out[b] = acc[b] * (1.0f / (float)LEN) + bdec[0];
}

extern "C" void kernel_launch(void* const* d_in, const int* in_sizes, int n_in,
                              void* d_out, int out_size, void* d_ws, size_t ws_size,
                              hipStream_t stream) {
    const float* u          = (const float*)d_in[0];
    const float* log_dt     = (const float*)d_in[1];
    const float* log_A_real = (const float*)d_in[2];
    const float* A_imag     = (const float*)d_in[3];
    const float* B_re       = (const float*)d_in[4];
    const float* B_im       = (const float*)d_in[5];
    const float* C_re       = (const float*)d_in[6];
    const float* C_im       = (const float*)d_in[7];
    const float* Dp         = (const float*)d_in[8];
    const float* W1         = (const float*)d_in[9];
    const float* b1         = (const float*)d_in[10];
    const float* Wdec       = (const float*)d_in[11];
    const float* bdec       = (const float*)d_in[12];
    float* out = (float*)d_out;

    float* w = (float*)d_ws;
    float* K      = w;                                    // 128*1024 f32
    float* acc    = K + (size_t)D_MODEL * LEN;            // 64 floats
    short* pgT    = (short*)(acc + 64);                   // [b][l][d] bf16: 32*1024*128
    short* w1bf   = pgT + (size_t)BATCH * LEN * D_MODEL;  // 256*128 bf16

    k_genK2<<<D_MODEL * 8, 256, 0, stream>>>(log_dt, log_A_real, A_imag, B_re, B_im,
                                             C_re, C_im, W1, w1bf, K, acc);
    k_conv2<<<D_MODEL * 8, 256, 0, stream>>>(u, K, Dp, pgT);
    k_glu_mfma<<<dim3(LEN / 32, BATCH), 256, 0, stream>>>(pgT, w1bf, b1, Wdec, acc);
    k_finish<<<1, 64, 0, stream>>>(acc, bdec, out);
}

// Round 5
// 141.428 us; speedup vs baseline: 1.9274x; 1.2851x over previous
//
#include <hip/hip_runtime.h>
#include <hip/hip_bf16.h>
#include <math.h>

#define D_MODEL 128
#define D_STATE 64
#define LEN 1024
#define BATCH 32

typedef short short8 __attribute__((ext_vector_type(8)));
typedef float f32x4 __attribute__((ext_vector_type(4)));

union PackU { uint4 u; short8 s; };

// ---------------- helpers ----------------
__device__ __forceinline__ float gelu_cheb(float x) {
    float t = (2.0f * x - 10.0f) * 0.05f;   // (2x - (hi+lo)) / (hi-lo), lo=-5 hi=15
    float r = 6.04831644882f + 8.094460228971f * t;
    float tm1 = 1.0f, tc = t;
    float t2 = 2.0f * t * tc - tm1; r += 1.371512430522f  * t2;
    float t3 = 2.0f * t * t2 - tc;  r += -0.740775295685f * t3;
    float t4 = 2.0f * t * t3 - t2;  r += 0.134773988002f  * t4;
    float t5 = 2.0f * t * t4 - t3;  r += 0.126019270103f  * t5;
    float t6 = 2.0f * t * t5 - t4;  r += -0.239569101196f * t6;
    return r;
}

__device__ __forceinline__ unsigned f2bf(float f) {  // f32 -> bf16 bits, RNE
    unsigned u = __float_as_uint(f);
    return (u + 0x7FFFu + ((u >> 16) & 1u)) >> 16;
}

// ---------------- Kernel 1: fused params + K via chunked recurrence ----------------
__global__ __launch_bounds__(256) void k_genK2(const float* __restrict__ log_dt,
                                               const float* __restrict__ log_A_real,
                                               const float* __restrict__ A_imag,
                                               const float* __restrict__ B_re,
                                               const float* __restrict__ B_im,
                                               const float* __restrict__ C_re,
                                               const float* __restrict__ C_im,
                                               const float* __restrict__ W1,
                                               short* __restrict__ w1bf,
                                               float* __restrict__ K) {
    int bid = blockIdx.x;             // 1024 = 128 d * 8 oct
    int d = bid >> 3, oct = bid & 7;
    int t = threadIdx.x;

    if (t < 32) { int i = bid * 32 + t; w1bf[i] = (short)f2bf(W1[i]); }

    int w = t >> 6, lane = t & 63;
    int idx = d * D_STATE + lane;
    float dt  = expf(log_dt[d]);
    float Are = -expf(log_A_real[idx]);
    float Aim = A_imag[idx];
    float dre = Are * dt, dim = Aim * dt;
    float e = expf(dre);
    float sn, cs; sincosf(dim, &sn, &cs);
    float zre = e * cs, zim = e * sn;                 // z = A_bar
    float numr = zre - 1.0f, numi = zim;
    float inv = 1.0f / (Are * Are + Aim * Aim);
    float qr = (numr * Are + numi * Aim) * inv;
    float qi = (numi * Are - numr * Aim) * inv;
    float Br = B_re[idx], Bi = B_im[idx];
    float Bbr = qr * Br - qi * Bi;
    float Bbi = qr * Bi + qi * Br;
    float Cr = C_re[idx], Ci = C_im[idx];
    float ar = Cr * Bbr - Ci * Bbi;
    float ai = Cr * Bbi + Ci * Bbr;

    int c = oct * 4 + w;
    int l0 = 32 * c;
    float fl0 = (float)l0;
    float pre = 0.f, pim = 0.f;
    if (dre * fl0 > -20.f) {                          // alive at chunk start
        float e0 = expf(dre * fl0);
        float s0, c0; sincosf(dim * fl0, &s0, &c0);
        pre = e0 * (ar * c0 - ai * s0);
        pim = e0 * (ar * s0 + ai * c0);
    }

    float kept = 0.f;
#pragma unroll
    for (int r = 0; r < 32; ++r) {
        float s = pre;
#pragma unroll
        for (int mm = 1; mm < 64; mm <<= 1) s += __shfl_xor(s, mm, 64);
        if (lane == r) kept = s;
        float nre = pre * zre - pim * zim;
        pim = pre * zim + pim * zre;
        pre = nre;
    }
    if (lane < 32) K[(size_t)d * LEN + l0 + lane] = kept;
}

// ---------------- Kernel 2: Toeplitz MFMA conv + skip + GELU (zero-tile skip) ----------------
// out[b,d,l] = sum_j u[b,d,j] * Kp[1023 + j - l], Kp zero above 1023.
// Tile (I, ks) is entirely zero iff 2*ks > I (all Kp indices >= 1024) -> skip.
// A-frag parity trick: 2 dword-pair copies P0/P1; y = S0>>1; 4 ds_read per frag.
#define US_STRIDE 1032
__global__ __launch_bounds__(256) void k_conv2(const float* __restrict__ u,
                                               const float* __restrict__ K,
                                               const float* __restrict__ Dp,
                                               short* __restrict__ pgT) {
    __shared__ unsigned P[2][1027];               // [0]=even-start copy, [1]=odd
    __shared__ __align__(16) short Us[16][US_STRIDE];
    int bid = blockIdx.x;                         // 128 d * 2 nh * 4 sq
    int d  = bid >> 3;
    int nh = (bid >> 2) & 1;
    int sq = bid & 3;
    int t = threadIdx.x;

    // zero pad region (elements >= 1024 read as 0)
    for (int y = 512 + t; y < 1027; y += 256) { P[0][y] = 0u; P[1][y] = 0u; }

    // fill P0/P1 from K[d]
    {
        const float* kp = K + (size_t)d * LEN;
        float4 kv = ((const float4*)kp)[t];
        unsigned e0 = f2bf(kv.x), e1 = f2bf(kv.y), e2 = f2bf(kv.z), e3 = f2bf(kv.w);
        unsigned e4 = (t < 255) ? f2bf(kp[4 * t + 4]) : 0u;
        P[0][2 * t]     = e0 | (e1 << 16);
        P[0][2 * t + 1] = e2 | (e3 << 16);
        P[1][2 * t]     = e1 | (e2 << 16);
        P[1][2 * t + 1] = e3 | (e4 << 16);
    }

    // stage Us[b][j] bf16
    {
        int r = t >> 4, c0 = (t & 15) * 64;
        const float* up = u + ((size_t)(nh * 16 + r) * D_MODEL + d) * LEN;
#pragma unroll
        for (int i = 0; i < 8; ++i) {
            float4 va = *(const float4*)&up[c0 + 8 * i];
            float4 vb = *(const float4*)&up[c0 + 8 * i + 4];
            short8 wv;
            wv[0] = (short)f2bf(va.x); wv[1] = (short)f2bf(va.y);
            wv[2] = (short)f2bf(va.z); wv[3] = (short)f2bf(va.w);
            wv[4] = (short)f2bf(vb.x); wv[5] = (short)f2bf(vb.y);
            wv[6] = (short)f2bf(vb.z); wv[7] = (short)f2bf(vb.w);
            *(short8*)&Us[r][c0 + 8 * i] = wv;
        }
    }
    __syncthreads();

    int wvu = __builtin_amdgcn_readfirstlane(t >> 6);   // wave-uniform SGPR
    int lane = t & 63;
    int m16 = lane & 15, q = lane >> 4;
    const unsigned* Pc = (m16 & 1) ? &P[0][0] : &P[1][0];   // odd m16 -> S0 even -> P0

    unsigned y0[4];
    f32x4 accv[4];
#pragma unroll
    for (int j = 0; j < 4; ++j) {
        int I = sq + 4 * (wvu + 4 * j);
        int S0 = 1023 + 8 * q - 16 * I - m16;     // >= 0
        y0[j] = ((unsigned)S0) >> 1;
        accv[j] = (f32x4){0.f, 0.f, 0.f, 0.f};
    }

#pragma unroll
    for (int ks = 0; ks < 32; ++ks) {
        short8 bfrag = *(const short8*)&Us[m16][32 * ks + 8 * q];
#pragma unroll
        for (int j = 0; j < 4; ++j) {
            int I = sq + 4 * (wvu + 4 * j);
            if (2 * ks <= I) {                    // else tile is exactly zero
                unsigned y = y0[j] + 16 * ks;
                PackU pu;
                pu.u.x = Pc[y]; pu.u.y = Pc[y + 1]; pu.u.z = Pc[y + 2]; pu.u.w = Pc[y + 3];
                accv[j] = __builtin_amdgcn_mfma_f32_16x16x32_bf16(pu.s, bfrag, accv[j], 0, 0, 0);
            }
        }
    }

    // epilogue: C col = m16 = batch-in-half, row = 4q+r = l offset in tile
    float Dd = Dp[d];
    int b = nh * 16 + m16;
    const float* ug = u + ((size_t)b * D_MODEL + d) * LEN;
#pragma unroll
    for (int j = 0; j < 4; ++j) {
        int I = sq + 4 * (wvu + 4 * j);
        int l0 = 16 * I + 4 * q;
        float4 u4 = *(const float4*)&ug[l0];
        float v0 = gelu_cheb(accv[j][0] + u4.x * Dd);
        float v1 = gelu_cheb(accv[j][1] + u4.y * Dd);
        float v2 = gelu_cheb(accv[j][2] + u4.z * Dd);
        float v3 = gelu_cheb(accv[j][3] + u4.w * Dd);
        size_t base = ((size_t)b * LEN + l0) * D_MODEL + d;
        pgT[base + 0 * D_MODEL] = (short)f2bf(v0);
        pgT[base + 1 * D_MODEL] = (short)f2bf(v1);
        pgT[base + 2 * D_MODEL] = (short)f2bf(v2);
        pgT[base + 3 * D_MODEL] = (short)f2bf(v3);
    }
}

// ---------------- Kernel 3: MFMA GEMM + GLU gate + pooling; no atomics ----------------
// C[o, l] = sum_k W1[o,k] * pgT[b,l,k]; 64-l tiles, A-frags hoisted to registers,
// per-block partial written to private acc2[b][lc] slot.
__global__ __launch_bounds__(256) void k_glu_mfma(const short* __restrict__ pgT,
                                                  const short* __restrict__ w1bf,
                                                  const float* __restrict__ b1,
                                                  const float* __restrict__ Wdec,
                                                  float* __restrict__ acc2) {
    __shared__ float red[4];
    int b = blockIdx.y;
    int lc = blockIdx.x;
    int l0 = lc * 64;
    int t = threadIdx.x;
    int wv = t >> 6, lane = t & 63;
    int m = lane & 15, q = lane >> 4;

    const short* wA0 = w1bf + ((2 * wv + 0) * 16 + m) * D_MODEL;
    const short* wA1 = w1bf + ((2 * wv + 1) * 16 + m) * D_MODEL;

    // hoist all A-fragments (w1bf is L2-hot)
    short8 aA0[4], aA1[4], aB0[4], aB1[4];
#pragma unroll
    for (int kki = 0; kki < 4; ++kki) {
        int ko = kki * 32 + q * 8;
        aA0[kki] = *(const short8*)(wA0 + ko);
        aA1[kki] = *(const short8*)(wA1 + ko);
        aB0[kki] = *(const short8*)(wA0 + 128 * D_MODEL + ko);
        aB1[kki] = *(const short8*)(wA1 + 128 * D_MODEL + ko);
    }

    const short* pgb = pgT + ((size_t)b * LEN + l0) * D_MODEL;

    f32x4 accA[2][4], accB[2][4];
#pragma unroll
    for (int p = 0; p < 2; ++p)
#pragma unroll
        for (int nt = 0; nt < 4; ++nt) {
            accA[p][nt] = (f32x4){0.f, 0.f, 0.f, 0.f};
            accB[p][nt] = (f32x4){0.f, 0.f, 0.f, 0.f};
        }

#pragma unroll
    for (int kki = 0; kki < 4; ++kki) {
        int ko = kki * 32 + q * 8;
        short8 bfr[4];
#pragma unroll
        for (int nt = 0; nt < 4; ++nt)
            bfr[nt] = *(const short8*)&pgb[(size_t)(nt * 16 + m) * D_MODEL + ko];
#pragma unroll
        for (int nt = 0; nt < 4; ++nt) {
            accA[0][nt] = __builtin_amdgcn_mfma_f32_16x16x32_bf16(aA0[kki], bfr[nt], accA[0][nt], 0, 0, 0);
            accA[1][nt] = __builtin_amdgcn_mfma_f32_16x16x32_bf16(aA1[kki], bfr[nt], accA[1][nt], 0, 0, 0);
            accB[0][nt] = __builtin_amdgcn_mfma_f32_16x16x32_bf16(aB0[kki], bfr[nt], accB[0][nt], 0, 0, 0);
            accB[1][nt] = __builtin_amdgcn_mfma_f32_16x16x32_bf16(aB1[kki], bfr[nt], accB[1][nt], 0, 0, 0);
        }
    }

    float s = 0.f;
#pragma unroll
    for (int p = 0; p < 2; ++p) {
        int oA = (2 * wv + p) * 16 + q * 4;
#pragma unroll
        for (int r = 0; r < 4; ++r) {
            int o = oA + r;
            float wd  = Wdec[o];
            float ba  = b1[o];
            float bb1 = b1[o + 128];
#pragma unroll
            for (int nt = 0; nt < 4; ++nt) {
                float aa  = accA[p][nt][r] + ba;
                float bbv = accB[p][nt][r] + bb1;
                float g = fminf(fmaxf(0.25f * bbv + 0.5f, 0.f), 1.f);
                s += wd * aa * g;
            }
        }
    }
#pragma unroll
    for (int off = 32; off > 0; off >>= 1) s += __shfl_down(s, off, 64);
    if (lane == 0) red[wv] = s;
    __syncthreads();
    if (t == 0) acc2[b * 16 + lc] = red[0] + red[1] + red[2] + red[3];
}

// ---------------- Kernel 4: finalize ----------------
__global__ void k_finish(const float* __restrict__ acc2, const float* __restrict__ bdec,
                         float* __restrict__ out) {
    int b = threadIdx.x;
    if (b < BATCH) {
        float s = 0.f;
#pragma unroll
        for (int c = 0; c < 16; ++c) s += acc2[b * 16 + c];
        out[b] = s * (1.0f / (float)LEN) + bdec[0];
    }
}

extern "C" void kernel_launch(void* const* d_in, const int* in_sizes, int n_in,
                              void* d_out, int out_size, void* d_ws, size_t ws_size,
                              hipStream_t stream) {
    const float* u          = (const float*)d_in[0];
    const float* log_dt     = (const float*)d_in[1];
    const float* log_A_real = (const float*)d_in[2];
    const float* A_imag     = (const float*)d_in[3];
    const float* B_re       = (const float*)d_in[4];
    const float* B_im       = (const float*)d_in[5];
    const float* C_re       = (const float*)d_in[6];
    const float* C_im       = (const float*)d_in[7];
    const float* Dp         = (const float*)d_in[8];
    const float* W1         = (const float*)d_in[9];
    const float* b1         = (const float*)d_in[10];
    const float* Wdec       = (const float*)d_in[11];
    const float* bdec       = (const float*)d_in[12];
    float* out = (float*)d_out;

    float* w = (float*)d_ws;
    float* K      = w;                                    // 128*1024 f32
    float* acc2   = K + (size_t)D_MODEL * LEN;            // 32*16 floats
    short* pgT    = (short*)(acc2 + 512);                 // [b][l][d] bf16: 32*1024*128
    short* w1bf   = pgT + (size_t)BATCH * LEN * D_MODEL;  // 256*128 bf16

    k_genK2<<<D_MODEL * 8, 256, 0, stream>>>(log_dt, log_A_real, A_imag, B_re, B_im,
                                             C_re, C_im, W1, w1bf, K);
    k_conv2<<<D_MODEL * 8, 256, 0, stream>>>(u, K, Dp, pgT);
    k_glu_mfma<<<dim3(16, BATCH), 256, 0, stream>>>(pgT, w1bf, b1, Wdec, acc2);
    k_finish<<<1, 64, 0, stream>>>(acc2, bdec, out);
}

// Round 6
// 136.019 us; speedup vs baseline: 2.0040x; 1.0398x over previous
//
#include <hip/hip_runtime.h>
#include <hip/hip_bf16.h>
#include <math.h>

#define D_MODEL 128
#define D_STATE 64
#define LEN 1024
#define BATCH 32
#define KC_STRIDE 1056   // shorts per shifted copy (zero-padded Kp window)

typedef short short8 __attribute__((ext_vector_type(8)));
typedef short short4v __attribute__((ext_vector_type(4)));
typedef float f32x4 __attribute__((ext_vector_type(4)));

// ---------------- helpers ----------------
__device__ __forceinline__ float gelu_cheb(float x) {
    float t = (2.0f * x - 10.0f) * 0.05f;   // (2x - (hi+lo)) / (hi-lo), lo=-5 hi=15
    float r = 6.04831644882f + 8.094460228971f * t;
    float tm1 = 1.0f, tc = t;
    float t2 = 2.0f * t * tc - tm1; r += 1.371512430522f  * t2;
    float t3 = 2.0f * t * t2 - tc;  r += -0.740775295685f * t3;
    float t4 = 2.0f * t * t3 - t2;  r += 0.134773988002f  * t4;
    float t5 = 2.0f * t * t4 - t3;  r += 0.126019270103f  * t5;
    float t6 = 2.0f * t * t5 - t4;  r += -0.239569101196f * t6;
    return r;
}

__device__ __forceinline__ unsigned f2bf(float f) {  // f32 -> bf16 bits, RNE
    unsigned u = __float_as_uint(f);
    return (u + 0x7FFFu + ((u >> 16) & 1u)) >> 16;
}

__device__ __forceinline__ float bf2f(short s) {
    return __uint_as_float(((unsigned)(unsigned short)s) << 16);
}

// ---------------- Kernel 1: params + K via LDS-transpose recurrence ----------------
// K[d][l] = Re( sum_n a_n z_n^l ), z = exp(dtA). Wave w of block (d,oct) covers
// l in [oct*128 + w*32, +32): exact expf/sincosf start, then 32 complex-mul steps,
// writing Re(p) to Ls[l][n] each step (NO cross-lane shuffles). After barrier,
// threads t<128 sum row t with ds_read_b128. Side jobs: u f32->bf16 (16 elems/thread),
// W1 -> bf16 (32 elems/block).
__global__ __launch_bounds__(256) void k_genK3(const float* __restrict__ log_dt,
                                               const float* __restrict__ log_A_real,
                                               const float* __restrict__ A_imag,
                                               const float* __restrict__ B_re,
                                               const float* __restrict__ B_im,
                                               const float* __restrict__ C_re,
                                               const float* __restrict__ C_im,
                                               const float* __restrict__ W1,
                                               const float* __restrict__ u,
                                               short* __restrict__ w1bf,
                                               short* __restrict__ u_bf,
                                               float* __restrict__ K) {
    __shared__ float Ls[128][68];     // 34.8 KB; stride 68 dwords (16B-aligned rows)
    int bid = blockIdx.x;             // 1024 = 128 d * 8 oct
    int d = bid >> 3, oct = bid & 7;
    int t = threadIdx.x;

    // side job: W1 -> bf16
    if (t < 32) { int i = bid * 32 + t; w1bf[i] = (short)f2bf(W1[i]); }

    // side job: u f32 -> bf16, 16 elements per thread (covers u exactly)
    {
        size_t tid = (size_t)bid * 256 + t;
        const float4* src = (const float4*)(u + tid * 16);
        float4 a = src[0], b4 = src[1], c4 = src[2], d4 = src[3];
        uint4 o0, o1;
        o0.x = f2bf(a.x)  | (f2bf(a.y)  << 16);
        o0.y = f2bf(a.z)  | (f2bf(a.w)  << 16);
        o0.z = f2bf(b4.x) | (f2bf(b4.y) << 16);
        o0.w = f2bf(b4.z) | (f2bf(b4.w) << 16);
        o1.x = f2bf(c4.x) | (f2bf(c4.y) << 16);
        o1.y = f2bf(c4.z) | (f2bf(c4.w) << 16);
        o1.z = f2bf(d4.x) | (f2bf(d4.y) << 16);
        o1.w = f2bf(d4.z) | (f2bf(d4.w) << 16);
        uint4* dst = (uint4*)u_bf + tid * 2;
        dst[0] = o0; dst[1] = o1;
    }

    int w = t >> 6, lane = t & 63;
    int idx = d * D_STATE + lane;
    float dt  = expf(log_dt[d]);
    float Are = -expf(log_A_real[idx]);
    float Aim = A_imag[idx];
    float dre = Are * dt, dim = Aim * dt;
    float e = expf(dre);
    float sn, cs; sincosf(dim, &sn, &cs);
    float zre = e * cs, zim = e * sn;                 // z = A_bar
    float numr = zre - 1.0f, numi = zim;
    float inv = 1.0f / (Are * Are + Aim * Aim);
    float qr = (numr * Are + numi * Aim) * inv;
    float qi = (numi * Are - numr * Aim) * inv;
    float Br = B_re[idx], Bi = B_im[idx];
    float Bbr = qr * Br - qi * Bi;
    float Bbi = qr * Bi + qi * Br;
    float Cr = C_re[idx], Ci = C_im[idx];
    float ar = Cr * Bbr - Ci * Bbi;
    float ai = Cr * Bbi + Ci * Bbr;

    int L0 = oct * 128 + w * 32;
    float fl0 = (float)L0;
    float pre = 0.f, pim = 0.f;
    if (dre * fl0 > -30.f) {                          // dead states contribute < 1e-13
        float e0 = expf(dre * fl0);
        float s0, c0; sincosf(dim * fl0, &s0, &c0);
        pre = e0 * (ar * c0 - ai * s0);
        pim = e0 * (ar * s0 + ai * c0);
    }

    int row0 = w * 32;
#pragma unroll
    for (int r = 0; r < 32; ++r) {
        Ls[row0 + r][lane] = pre;                     // consecutive lanes -> consecutive banks
        float nre = pre * zre - pim * zim;
        pim = pre * zim + pim * zre;
        pre = nre;
    }
    __syncthreads();

    if (t < 128) {
        f32x4 s4 = (f32x4){0.f, 0.f, 0.f, 0.f};
#pragma unroll
        for (int c = 0; c < 16; ++c) s4 += *(const f32x4*)&Ls[t][4 * c];
        K[(size_t)d * LEN + oct * 128 + t] = s4.x + s4.y + s4.z + s4.w;
    }
}

// ---------------- Kernel 2: Toeplitz MFMA conv + skip + GELU ----------------
// out[b,d,l] = sum_j u[b,d,j] * Kp[1023 + j - l], Kp zero above 1023.
// A-frag: 8-shift bf16 LDS copies Kc[c][x] = bf16(Kp[x+c]); copy select
// c = (7-m16)&7 is LANE-CONSTANT (8q,16I,32ks all == 0 mod 8) -> single
// aligned ds_read_b128 per frag, bank-balanced at stride 528 dwords.
// B-frag: direct global 16B loads from u_bf (L2/L3-hot). Zero tiles skipped
// via wave-uniform guard. Epilogue: skip from u_bf, GELU, pgT[b][l][d] bf16.
__global__ __launch_bounds__(256) void k_conv3(const float* __restrict__ K,
                                               const short* __restrict__ u_bf,
                                               const float* __restrict__ Dp,
                                               short* __restrict__ pgT) {
    __shared__ __align__(16) short Kc[8 * KC_STRIDE];   // 16.9 KB
    int bid = blockIdx.x;                 // 128 d * 2 nh * 4 sq
    int d  = bid >> 3;
    int nh = (bid >> 2) & 1;
    int sq = bid & 3;
    int t = threadIdx.x;

    // zero tail region (x >= 1016 may reach pad); 8 copies * 40 shorts = 160 dwords
    if (t < 160) {
        int c = t / 20, y = t - c * 20;
        ((unsigned*)&Kc[c * KC_STRIDE + 1016])[y] = 0u;
    }
    // build 8 shifted bf16 copies from K[d] (f32, L2-hot)
    {
        const float* kp = K + (size_t)d * LEN;
        float4 kv = ((const float4*)kp)[t];
        float vals[4] = {kv.x, kv.y, kv.z, kv.w};
#pragma unroll
        for (int mm = 0; mm < 4; ++mm) {
            int ei = 4 * t + mm;
            short bv = (short)f2bf(vals[mm]);
#pragma unroll
            for (int c = 0; c < 8; ++c) {
                int x = ei - c;
                if (x >= 0) Kc[c * KC_STRIDE + x] = bv;
            }
        }
    }
    __syncthreads();

    int wvu = __builtin_amdgcn_readfirstlane(t >> 6);   // wave-uniform SGPR
    int lane = t & 63;
    int m16 = lane & 15, q = lane >> 4;
    int cc = (7 - m16) & 7;                             // lane-constant copy index
    const short* Krow = Kc + cc * KC_STRIDE;
    const short* ub = u_bf + (((size_t)(nh * 16 + m16) * D_MODEL + d) << 10);

    int x0[4];
    f32x4 accv[4];
#pragma unroll
    for (int j = 0; j < 4; ++j) {
        int I = sq + 4 * (wvu + 4 * j);
        x0[j] = 1023 + 8 * q - 16 * I - m16 - cc;       // >= 0, == 0 mod 8
        accv[j] = (f32x4){0.f, 0.f, 0.f, 0.f};
    }

    int ks_end = (sq + 4 * wvu + 48) / 2 + 1;           // last alive ks for wave's max I
    if (ks_end > 32) ks_end = 32;
    for (int ks = 0; ks < ks_end; ++ks) {
        short8 bfrag = *(const short8*)&ub[32 * ks + 8 * q];   // global, 16B/lane
#pragma unroll
        for (int j = 0; j < 4; ++j) {
            int I = sq + 4 * (wvu + 4 * j);
            if (2 * ks <= I) {                          // wave-uniform; else tile exactly 0
                short8 afrag = *(const short8*)&Krow[x0[j] + 32 * ks];
                accv[j] = __builtin_amdgcn_mfma_f32_16x16x32_bf16(afrag, bfrag, accv[j], 0, 0, 0);
            }
        }
    }

    // epilogue: C col = m16 = batch-in-half, row = 4q+r = l offset in tile
    float Dd = Dp[d];
    int b = nh * 16 + m16;
#pragma unroll
    for (int j = 0; j < 4; ++j) {
        int I = sq + 4 * (wvu + 4 * j);
        int l0 = 16 * I + 4 * q;
        short4v us = *(const short4v*)&ub[l0];          // skip term from u_bf (8B)
        float v0 = gelu_cheb(accv[j][0] + bf2f(us[0]) * Dd);
        float v1 = gelu_cheb(accv[j][1] + bf2f(us[1]) * Dd);
        float v2 = gelu_cheb(accv[j][2] + bf2f(us[2]) * Dd);
        float v3 = gelu_cheb(accv[j][3] + bf2f(us[3]) * Dd);
        size_t basep = ((size_t)b * LEN + l0) * D_MODEL + d;
        pgT[basep + 0 * D_MODEL] = (short)f2bf(v0);
        pgT[basep + 1 * D_MODEL] = (short)f2bf(v1);
        pgT[basep + 2 * D_MODEL] = (short)f2bf(v2);
        pgT[basep + 3 * D_MODEL] = (short)f2bf(v3);
    }
}

// ---------------- Kernel 3: MFMA GEMM + GLU gate + pooling; no atomics ----------------
__global__ __launch_bounds__(256) void k_glu_mfma(const short* __restrict__ pgT,
                                                  const short* __restrict__ w1bf,
                                                  const float* __restrict__ b1,
                                                  const float* __restrict__ Wdec,
                                                  float* __restrict__ acc2) {
    __shared__ float red[4];
    int b = blockIdx.y;
    int lc = blockIdx.x;
    int l0 = lc * 64;
    int t = threadIdx.x;
    int wv = t >> 6, lane = t & 63;
    int m = lane & 15, q = lane >> 4;

    const short* wA0 = w1bf + ((2 * wv + 0) * 16 + m) * D_MODEL;
    const short* wA1 = w1bf + ((2 * wv + 1) * 16 + m) * D_MODEL;

    short8 aA0[4], aA1[4], aB0[4], aB1[4];
#pragma unroll
    for (int kki = 0; kki < 4; ++kki) {
        int ko = kki * 32 + q * 8;
        aA0[kki] = *(const short8*)(wA0 + ko);
        aA1[kki] = *(const short8*)(wA1 + ko);
        aB0[kki] = *(const short8*)(wA0 + 128 * D_MODEL + ko);
        aB1[kki] = *(const short8*)(wA1 + 128 * D_MODEL + ko);
    }

    const short* pgb = pgT + ((size_t)b * LEN + l0) * D_MODEL;

    f32x4 accA[2][4], accB[2][4];
#pragma unroll
    for (int p = 0; p < 2; ++p)
#pragma unroll
        for (int nt = 0; nt < 4; ++nt) {
            accA[p][nt] = (f32x4){0.f, 0.f, 0.f, 0.f};
            accB[p][nt] = (f32x4){0.f, 0.f, 0.f, 0.f};
        }

#pragma unroll
    for (int kki = 0; kki < 4; ++kki) {
        int ko = kki * 32 + q * 8;
        short8 bfr[4];
#pragma unroll
        for (int nt = 0; nt < 4; ++nt)
            bfr[nt] = *(const short8*)&pgb[(size_t)(nt * 16 + m) * D_MODEL + ko];
#pragma unroll
        for (int nt = 0; nt < 4; ++nt) {
            accA[0][nt] = __builtin_amdgcn_mfma_f32_16x16x32_bf16(aA0[kki], bfr[nt], accA[0][nt], 0, 0, 0);
            accA[1][nt] = __builtin_amdgcn_mfma_f32_16x16x32_bf16(aA1[kki], bfr[nt], accA[1][nt], 0, 0, 0);
            accB[0][nt] = __builtin_amdgcn_mfma_f32_16x16x32_bf16(aB0[kki], bfr[nt], accB[0][nt], 0, 0, 0);
            accB[1][nt] = __builtin_amdgcn_mfma_f32_16x16x32_bf16(aB1[kki], bfr[nt], accB[1][nt], 0, 0, 0);
        }
    }

    float s = 0.f;
#pragma unroll
    for (int p = 0; p < 2; ++p) {
        int oA = (2 * wv + p) * 16 + q * 4;
#pragma unroll
        for (int r = 0; r < 4; ++r) {
            int o = oA + r;
            float wd  = Wdec[o];
            float ba  = b1[o];
            float bb1 = b1[o + 128];
#pragma unroll
            for (int nt = 0; nt < 4; ++nt) {
                float aa  = accA[p][nt][r] + ba;
                float bbv = accB[p][nt][r] + bb1;
                float g = fminf(fmaxf(0.25f * bbv + 0.5f, 0.f), 1.f);
                s += wd * aa * g;
            }
        }
    }
#pragma unroll
    for (int off = 32; off > 0; off >>= 1) s += __shfl_down(s, off, 64);
    if (lane == 0) red[wv] = s;
    __syncthreads();
    if (t == 0) acc2[b * 16 + lc] = red[0] + red[1] + red[2] + red[3];
}

// ---------------- Kernel 4: finalize ----------------
__global__ void k_finish(const float* __restrict__ acc2, const float* __restrict__ bdec,
                         float* __restrict__ out) {
    int b = threadIdx.x;
    if (b < BATCH) {
        float s = 0.f;
#pragma unroll
        for (int c = 0; c < 16; ++c) s += acc2[b * 16 + c];
        out[b] = s * (1.0f / (float)LEN) + bdec[0];
    }
}

extern "C" void kernel_launch(void* const* d_in, const int* in_sizes, int n_in,
                              void* d_out, int out_size, void* d_ws, size_t ws_size,
                              hipStream_t stream) {
    const float* u          = (const float*)d_in[0];
    const float* log_dt     = (const float*)d_in[1];
    const float* log_A_real = (const float*)d_in[2];
    const float* A_imag     = (const float*)d_in[3];
    const float* B_re       = (const float*)d_in[4];
    const float* B_im       = (const float*)d_in[5];
    const float* C_re       = (const float*)d_in[6];
    const float* C_im       = (const float*)d_in[7];
    const float* Dp         = (const float*)d_in[8];
    const float* W1         = (const float*)d_in[9];
    const float* b1         = (const float*)d_in[10];
    const float* Wdec       = (const float*)d_in[11];
    const float* bdec       = (const float*)d_in[12];
    float* out = (float*)d_out;

    float* w = (float*)d_ws;
    float* K      = w;                                    // 128*1024 f32
    float* acc2   = K + (size_t)D_MODEL * LEN;            // 512 floats
    short* u_bf   = (short*)(acc2 + 512);                 // [b][d][l] bf16: 32*128*1024
    short* pgT    = u_bf + (size_t)BATCH * D_MODEL * LEN; // [b][l][d] bf16
    short* w1bf   = pgT + (size_t)BATCH * LEN * D_MODEL;  // 256*128 bf16

    k_genK3<<<D_MODEL * 8, 256, 0, stream>>>(log_dt, log_A_real, A_imag, B_re, B_im,
                                             C_re, C_im, W1, u, w1bf, u_bf, K);
    k_conv3<<<D_MODEL * 8, 256, 0, stream>>>(K, u_bf, Dp, pgT);
    k_glu_mfma<<<dim3(16, BATCH), 256, 0, stream>>>(pgT, w1bf, b1, Wdec, acc2);
    k_finish<<<1, 64, 0, stream>>>(acc2, bdec, out);
}